// Round 1
// baseline (527.841 us; speedup 1.0000x reference)
//
#include <hip/hip_runtime.h>

#define LN    2586
#define ZETA  128
#define GAMMA 128
#define NBATCH 256
#define BK    32
#define NT    81   // ceil(2586/32), 81*32 = 2592

typedef __attribute__((ext_vector_type(8))) short short8;
typedef __attribute__((ext_vector_type(4))) float float4v;

// f32 -> bf16 (round to nearest even), bit-level (no header dependency)
static __device__ __forceinline__ unsigned short f2bf(float f) {
    union { float f; unsigned u; } v; v.f = f;
    unsigned r = v.u + 0x7FFF + ((v.u >> 16) & 1);
    return (unsigned short)(r >> 16);
}

__global__ __launch_bounds__(512, 2)
void fused_gemm_bias_kernel(const float* __restrict__ M,
                            const float* __restrict__ Wc,
                            const float* __restrict__ Wp,
                            float* __restrict__ out) {
    // A = Wc tile [g=128][k=32] bf16, row-padded to 40 elems (80 B, 20 banks)
    // B = M tile transposed [z=128][k=32] bf16, same padding
    __shared__ unsigned short Abuf[2][128][40];
    __shared__ unsigned short Bbuf[2][128][40];

    const int b    = blockIdx.x;
    const int tid  = threadIdx.x;
    const int lane = tid & 63;
    const int wave = tid >> 6;

    const float* Mb = M + (size_t)b * LN * ZETA;

    // --- staging maps ---
    // M: thread owns one z column, 8 consecutive k rows
    const int mz  = tid & 127;   // z
    const int mkj = tid >> 7;    // 0..3 : k-subblock of 8
    // Wc: thread owns one g row, 8 consecutive k cols
    const int ag    = tid >> 2;  // 0..127 : g
    const int apart = tid & 3;   // 0..3 : k-subblock of 8

    // --- compute maps: 8 waves = 4 (g) x 2 (z); wave tile 32x64 ---
    const int gbase = (wave >> 1) * 32;
    const int zbase = (wave & 1) * 64;
    const int lr = lane & 15;          // fragment row (A) / col (B)
    const int lk = (lane >> 4) * 8;    // fragment k offset (contiguous 8)

    float4v acc[2][4];
    #pragma unroll
    for (int i = 0; i < 2; ++i)
        #pragma unroll
        for (int j = 0; j < 4; ++j)
            acc[i][j] = float4v{0.f, 0.f, 0.f, 0.f};

    float mreg[8], wreg[8];

    // ---- prologue: stage tile 0 into buf 0 ----
    {
        #pragma unroll
        for (int j = 0; j < 8; ++j) {
            int k = mkj * 8 + j;
            if (k > LN - 1) k = LN - 1;            // clamp (never triggers here)
            mreg[j] = Mb[(size_t)k * ZETA + mz];
        }
        #pragma unroll
        for (int j = 0; j < 8; ++j) {
            int c = apart * 8 + j;
            wreg[j] = (c < LN) ? Wc[(size_t)ag * LN + c] : 0.f;
        }
        union { short8 v; unsigned short s[8]; } pm, pw;
        #pragma unroll
        for (int j = 0; j < 8; ++j) { pm.s[j] = f2bf(mreg[j]); pw.s[j] = f2bf(wreg[j]); }
        *(short8*)&Bbuf[0][mz][mkj * 8]  = pm.v;
        *(short8*)&Abuf[0][ag][apart * 8] = pw.v;
    }
    __syncthreads();

    // ---- main K loop: double-buffered, 1 barrier / iter ----
    for (int t = 0; t < NT; ++t) {
        const int  cur      = t & 1;
        const int  nxt      = cur ^ 1;
        const bool has_next = (t + 1 < NT);

        // 1. issue next tile's global loads early (hide HBM latency under MFMA)
        if (has_next) {
            const int k0 = (t + 1) * BK;
            #pragma unroll
            for (int j = 0; j < 8; ++j) {
                int k = k0 + mkj * 8 + j;
                if (k > LN - 1) k = LN - 1;        // tail: value killed by Wc pad = 0
                mreg[j] = Mb[(size_t)k * ZETA + mz];
            }
            #pragma unroll
            for (int j = 0; j < 8; ++j) {
                int c = k0 + apart * 8 + j;
                wreg[j] = (c < LN) ? Wc[(size_t)ag * LN + c] : 0.f;
            }
        }

        // 2. fragments + MFMA on current buffer
        short8 afrag[2], bfrag[4];
        #pragma unroll
        for (int mi = 0; mi < 2; ++mi)
            afrag[mi] = *(const short8*)&Abuf[cur][gbase + mi * 16 + lr][lk];
        #pragma unroll
        for (int ni = 0; ni < 4; ++ni)
            bfrag[ni] = *(const short8*)&Bbuf[cur][zbase + ni * 16 + lr][lk];
        #pragma unroll
        for (int mi = 0; mi < 2; ++mi)
            #pragma unroll
            for (int ni = 0; ni < 4; ++ni)
                acc[mi][ni] = __builtin_amdgcn_mfma_f32_16x16x32_bf16(
                    afrag[mi], bfrag[ni], acc[mi][ni], 0, 0, 0);

        // 3. convert + write next tile into other buffer
        if (has_next) {
            union { short8 v; unsigned short s[8]; } pm, pw;
            #pragma unroll
            for (int j = 0; j < 8; ++j) { pm.s[j] = f2bf(mreg[j]); pw.s[j] = f2bf(wreg[j]); }
            *(short8*)&Bbuf[nxt][mz][mkj * 8]  = pm.v;
            *(short8*)&Abuf[nxt][ag][apart * 8] = pw.v;
        }
        __syncthreads();
    }

    // ---- epilogue: D + Wp -> out ----
    float* outb = out + (size_t)b * GAMMA * ZETA;
    #pragma unroll
    for (int mi = 0; mi < 2; ++mi) {
        #pragma unroll
        for (int ni = 0; ni < 4; ++ni) {
            #pragma unroll
            for (int r = 0; r < 4; ++r) {
                const int g = gbase + mi * 16 + (lane >> 4) * 4 + r;
                const int z = zbase + ni * 16 + lr;
                outb[g * ZETA + z] = acc[mi][ni][r] + Wp[g * ZETA + z];
            }
        }
    }
}

extern "C" void kernel_launch(void* const* d_in, const int* in_sizes, int n_in,
                              void* d_out, int out_size, void* d_ws, size_t ws_size,
                              hipStream_t stream) {
    const float* M  = (const float*)d_in[0];   // [256][2586][128] f32
    const float* Wc = (const float*)d_in[1];   // [128][2586] f32
    const float* Wp = (const float*)d_in[2];   // [128][128] f32
    float* out = (float*)d_out;                // [256][128][128] f32

    fused_gemm_bias_kernel<<<NBATCH, 512, 0, stream>>>(M, Wc, Wp, out);
}